// Round 11
// baseline (210.674 us; speedup 1.0000x reference)
//
#include <hip/hip_runtime.h>
#include <stdint.h>

// GAT layer: N nodes, E edges, IN=128 -> H*C=128, H=4 heads, C=32.
// Pipeline (fused, atomic-free partition, split sort/gather):
//   k_wprep : Wt[n][k] = bf16(W[k][n])
//   k_gemm  : h(bf16) = bf16(x) @ Wt via mfma_f32_16x16x32_bf16 (Wt in swizzled LDS)
//             + fused alpha (asrc/adst via 16-lane shfl reduce of acc regs)
//             + LDS repack -> wide coalesced h stores (64 B/lane)
//   k_hist  : per-(bucket,block) edge histogram via LDS (bucket = dst>>6, 64 nodes)
//   k_scanA/B/C : hierarchical exclusive scan of cnt2 -> exact (bucket,block) bases
//   k_fill2 : deterministic scatter into ebuf, LDS cursors only (no global atomics)
//   k_csr2  : per-bucket counting sort -> global adj (sorted src) + packed bf16
//             per-head weights psw (8 B/edge) + per-node inv_denom & pself.
//             exp computed ONCE per edge here. Softmax without max-shift: logits
//             bounded, softmax shift-invariant. ~2.5 KB LDS -> high occupancy,
//             no capacity limit.
//   k_gather: wave-per-node pure gather-accumulate: no LDS, no exp, 8-deep
//             unrolled independent h-row gathers (latency hiding), final
//             multiply by precomputed 1/denom.

#define NBLK 512    // partition blocks
#define BKT 64      // dst nodes per bucket

typedef __bf16 bf16x8 __attribute__((ext_vector_type(8)));
typedef float f32x4 __attribute__((ext_vector_type(4)));

__device__ __forceinline__ float lrelu(float x) { return x >= 0.f ? x : 0.2f * x; }
__device__ __forceinline__ float blo(unsigned u) { return __uint_as_float(u << 16); }
__device__ __forceinline__ float bhi(unsigned u) { return __uint_as_float(u & 0xffff0000u); }
__device__ __forceinline__ unsigned pk2(float a, float b) {
  unsigned short ua = __builtin_bit_cast(unsigned short, (__bf16)a);
  unsigned short ub = __builtin_bit_cast(unsigned short, (__bf16)b);
  return ((unsigned)ub << 16) | ua;
}

__global__ __launch_bounds__(256) void k_wprep(const float* __restrict__ W, __bf16* __restrict__ Wt) {
  int idx = blockIdx.x * 256 + threadIdx.x;   // grid = 64 blocks covers 128*128
  int nn = idx & 127, k = idx >> 7;
  Wt[nn * 128 + k] = (__bf16)W[k * 128 + nn];
}

__global__ __launch_bounds__(256) void k_gemm(const float* __restrict__ x, const __bf16* __restrict__ Wt,
                                              const float* __restrict__ a_src, const float* __restrict__ a_dst,
                                              __bf16* __restrict__ h, float* __restrict__ asrc,
                                              float* __restrict__ adst, int n) {
  __shared__ __align__(16) char Wl[32768];          // Wt[n][k] bf16, XOR-swizzled
  __shared__ __align__(16) __bf16 hbuf[4][16 * 128]; // per-wave bf16 output tile
  int t = threadIdx.x;
  {
    const float4* s4 = (const float4*)Wt;
    for (int i = t; i < 2048; i += 256) {
      int f = i << 4;
      int nr = f >> 8, c = f & 255;
      *(float4*)(Wl + ((nr << 8) | (c ^ ((nr & 7) << 4)))) = s4[i];
    }
  }
  __syncthreads();
  int wv = t >> 6, lane = t & 63;
  int arow = lane & 15, ag = lane >> 4, c15 = lane & 15;
  float as_t[8], ad_t[8];
#pragma unroll
  for (int tile = 0; tile < 8; ++tile) {
    as_t[tile] = a_src[tile * 16 + c15];
    ad_t[tile] = a_dst[tile * 16 + c15];
  }
  int strip = blockIdx.x * 64 + wv * 16;
  int row = strip + arow;
  float4 fa[8];
  if (row < n) {
    const float4* xr = (const float4*)(x + (size_t)row * 128);
#pragma unroll
    for (int q = 0; q < 4; ++q) {
      fa[2 * q]     = xr[q * 8 + ag * 2];
      fa[2 * q + 1] = xr[q * 8 + ag * 2 + 1];
    }
  } else {
#pragma unroll
    for (int q = 0; q < 8; ++q) fa[q] = make_float4(0.f, 0.f, 0.f, 0.f);
  }
  bf16x8 af[4];
#pragma unroll
  for (int q = 0; q < 4; ++q) {
    af[q][0] = (__bf16)fa[2 * q].x;     af[q][1] = (__bf16)fa[2 * q].y;
    af[q][2] = (__bf16)fa[2 * q].z;     af[q][3] = (__bf16)fa[2 * q].w;
    af[q][4] = (__bf16)fa[2 * q + 1].x; af[q][5] = (__bf16)fa[2 * q + 1].y;
    af[q][6] = (__bf16)fa[2 * q + 1].z; af[q][7] = (__bf16)fa[2 * q + 1].w;
  }
  f32x4 acc[8];
#pragma unroll
  for (int tile = 0; tile < 8; ++tile) acc[tile] = (f32x4){0.f, 0.f, 0.f, 0.f};
#pragma unroll
  for (int q = 0; q < 4; ++q) {
    int gb = (q * 64) + (ag << 4);
#pragma unroll
    for (int tile = 0; tile < 8; ++tile) {
      int nn = tile * 16 + c15;
      bf16x8 bf = *(const bf16x8*)(Wl + ((nn << 8) | (gb ^ ((nn & 7) << 4))));
      acc[tile] = __builtin_amdgcn_mfma_f32_16x16x32_bf16(af[q], bf, acc[tile], 0, 0, 0);
    }
  }
  // fused alpha: per (head, r) reduce acc over the 16 c15 lanes
#pragma unroll
  for (int hh = 0; hh < 4; ++hh) {
#pragma unroll
    for (int r = 0; r < 4; ++r) {
      float vps = acc[2 * hh][r] * as_t[2 * hh] + acc[2 * hh + 1][r] * as_t[2 * hh + 1];
      float vpd = acc[2 * hh][r] * ad_t[2 * hh] + acc[2 * hh + 1][r] * ad_t[2 * hh + 1];
#pragma unroll
      for (int m = 1; m < 16; m <<= 1) {
        vps += __shfl_xor(vps, m, 64);
        vpd += __shfl_xor(vpd, m, 64);
      }
      if (c15 == 0) {
        int ro = strip + ag * 4 + r;
        if (ro < n) { asrc[ro * 4 + hh] = vps; adst[ro * 4 + hh] = vpd; }
      }
    }
  }
  // repack acc -> bf16 LDS tile, then wide coalesced store (64 B per lane)
#pragma unroll
  for (int tile = 0; tile < 8; ++tile) {
#pragma unroll
    for (int r = 0; r < 4; ++r)
      hbuf[wv][(ag * 4 + r) * 128 + tile * 16 + c15] = (__bf16)acc[tile][r];
  }
  int rr = lane >> 2, qq = lane & 3;   // lane covers 64 B (32 bf16) of row rr
  int ro = strip + rr;
  if (ro < n) {
    const float4* src = (const float4*)&hbuf[wv][rr * 128 + qq * 32];
    float4* dst = (float4*)(h + (size_t)ro * 128 + qq * 32);
    dst[0] = src[0];
    dst[1] = src[1];
    dst[2] = src[2];
    dst[3] = src[3];
  }
}

// --- atomic-free bucketed edge partition: bucket = dst >> 6 (64 nodes) ---

__global__ __launch_bounds__(256) void k_hist(const int* __restrict__ ei, int* __restrict__ cnt2,
                                              int e, int NB, int CE) {
  __shared__ int hist[2048];
  int t = threadIdx.x, blk = blockIdx.x;
  for (int j = t; j < NB; j += 256) hist[j] = 0;
  __syncthreads();
  int i0 = blk * CE, i1 = min(e, i0 + CE);
  for (int i = i0 + t; i < i1; i += 256) atomicAdd(&hist[ei[e + i] >> 6], 1);
  __syncthreads();
  for (int j = t; j < NB; j += 256) cnt2[j * NBLK + blk] = hist[j];
}

__global__ __launch_bounds__(256) void k_scanA(int* __restrict__ cnt2, int* __restrict__ bsums, int m) {
  __shared__ int wsum[4];
  int t = threadIdx.x, i = blockIdx.x * 256 + t;
  int wv = t >> 6, lane = t & 63;
  int v = (i < m) ? cnt2[i] : 0;
  int sc = v;
#pragma unroll
  for (int ofs = 1; ofs < 64; ofs <<= 1) {
    int u = __shfl_up(sc, ofs, 64);
    if (lane >= ofs) sc += u;
  }
  if (lane == 63) wsum[wv] = sc;
  __syncthreads();
  int base = 0;
  for (int w = 0; w < wv; ++w) base += wsum[w];
  if (i < m) cnt2[i] = base + sc - v;
  if (t == 255) bsums[blockIdx.x] = base + sc;
}

__global__ __launch_bounds__(256) void k_scanB(int* __restrict__ bsums, int nbs) {
  __shared__ int wsum[4];
  int t = threadIdx.x, wv = t >> 6, lane = t & 63;
  int carry = 0;
  for (int c = 0; c < nbs; c += 256) {
    int i = c + t;
    int v = (i < nbs) ? bsums[i] : 0;
    int sc = v;
#pragma unroll
    for (int ofs = 1; ofs < 64; ofs <<= 1) {
      int u = __shfl_up(sc, ofs, 64);
      if (lane >= ofs) sc += u;
    }
    if (lane == 63) wsum[wv] = sc;
    __syncthreads();
    int base = carry;
    for (int w = 0; w < wv; ++w) base += wsum[w];
    if (i < nbs) bsums[i] = base + sc - v;
    carry += wsum[0] + wsum[1] + wsum[2] + wsum[3];
    __syncthreads();
  }
}

__global__ __launch_bounds__(256) void k_scanC(int* __restrict__ cnt2, const int* __restrict__ bsums,
                                               int* __restrict__ boffbg, int* __restrict__ off,
                                               int m, int NB, int n, int e) {
  int i = blockIdx.x * 256 + threadIdx.x;
  if (i < m) {
    int v = cnt2[i] + bsums[i >> 8];
    cnt2[i] = v;
    if ((i & (NBLK - 1)) == 0) boffbg[i / NBLK] = v;
  }
  if (i == 0) { boffbg[NB] = e; off[n] = e; }
}

__global__ __launch_bounds__(256) void k_fill2(const int* __restrict__ ei, const int* __restrict__ cnt2,
                                               unsigned* __restrict__ ebuf, int e, int NB, int CE) {
  __shared__ int cur[2048];
  int t = threadIdx.x, blk = blockIdx.x;
  for (int j = t; j < NB; j += 256) cur[j] = cnt2[j * NBLK + blk];
  __syncthreads();
  int i0 = blk * CE, i1 = min(e, i0 + CE);
  for (int i = i0 + t; i < i1; i += 256) {
    int s = ei[i], d = ei[e + i];
    int pos = atomicAdd(&cur[d >> 6], 1);    // LDS atomic only
    ebuf[pos] = ((unsigned)(d & 63) << 26) | (unsigned)s;
  }
}

// per-bucket counting sort -> global adj + packed weights + inv_denom/pself
__global__ __launch_bounds__(256) void k_csr2(const unsigned* __restrict__ ebuf, const int* __restrict__ boffbg,
                                              const float* __restrict__ asrc, const float* __restrict__ adst,
                                              int* __restrict__ off, int* __restrict__ adj,
                                              uint2* __restrict__ pswg, float* __restrict__ inv4,
                                              float* __restrict__ pself4, int n) {
  __shared__ __align__(16) float adstl[BKT * 4];
  __shared__ float ldenom[BKT * 4];
  __shared__ int lcnt[BKT], lcur[BKT];
  int b = blockIdx.x, t = threadIdx.x;
  int wv = t >> 6, lane = t & 63;
  int s0 = boffbg[b], s1 = boffbg[b + 1];
  int cnt = s1 - s0;
  int d0 = b * BKT;
  if (t < BKT) {
    lcnt[t] = 0;
    float4 ad = (d0 + t < n) ? ((const float4*)adst)[d0 + t] : make_float4(0.f, 0.f, 0.f, 0.f);
    ((float4*)adstl)[t] = ad;
    ldenom[t * 4 + 0] = 0.f; ldenom[t * 4 + 1] = 0.f;
    ldenom[t * 4 + 2] = 0.f; ldenom[t * 4 + 3] = 0.f;
  }
  __syncthreads();
  for (int j = t; j < cnt; j += 256) atomicAdd(&lcnt[ebuf[s0 + j] >> 26], 1);
  __syncthreads();
  if (wv == 0) {                       // 64-lane scan of bucket-local counts
    int v = lcnt[lane];
    int sc = v;
#pragma unroll
    for (int o = 1; o < 64; o <<= 1) {
      int u = __shfl_up(sc, o, 64);
      if (lane >= o) sc += u;
    }
    lcur[lane] = sc - v;
    if (d0 + lane < n) off[d0 + lane] = s0 + sc - v;
  }
  __syncthreads();
  // scatter: sorted src + 4 packed bf16 weights per edge (exp ONCE per edge)
  for (int j = t; j < cnt; j += 256) {
    unsigned u = ebuf[s0 + j];
    int dl = u >> 26;
    int s = (int)(u & 0x03FFFFFFu);
    float4 as = ((const float4*)asrc)[s];
    float p0 = __expf(lrelu(as.x + adstl[dl * 4 + 0]));
    float p1 = __expf(lrelu(as.y + adstl[dl * 4 + 1]));
    float p2 = __expf(lrelu(as.z + adstl[dl * 4 + 2]));
    float p3 = __expf(lrelu(as.w + adstl[dl * 4 + 3]));
    int pos = atomicAdd(&lcur[dl], 1);
    adj[s0 + pos] = s;
    pswg[s0 + pos] = make_uint2(pk2(p0, p1), pk2(p2, p3));
    atomicAdd(&ldenom[dl * 4 + 0], p0);
    atomicAdd(&ldenom[dl * 4 + 1], p1);
    atomicAdd(&ldenom[dl * 4 + 2], p2);
    atomicAdd(&ldenom[dl * 4 + 3], p3);
  }
  __syncthreads();
  if (t < BKT && d0 + t < n) {
    int d = d0 + t;
    float4 as = ((const float4*)asrc)[d];
    float4 ps;
    ps.x = __expf(lrelu(as.x + adstl[t * 4 + 0]));
    ps.y = __expf(lrelu(as.y + adstl[t * 4 + 1]));
    ps.z = __expf(lrelu(as.z + adstl[t * 4 + 2]));
    ps.w = __expf(lrelu(as.w + adstl[t * 4 + 3]));
    ((float4*)pself4)[d] = ps;
    float4 iv;
    iv.x = 1.f / (ldenom[t * 4 + 0] + ps.x);
    iv.y = 1.f / (ldenom[t * 4 + 1] + ps.y);
    iv.z = 1.f / (ldenom[t * 4 + 2] + ps.z);
    iv.w = 1.f / (ldenom[t * 4 + 3] + ps.w);
    ((float4*)inv4)[d] = iv;
  }
}

// wave-per-node pure gather-accumulate; no LDS, no exp, 8-deep MLP
__global__ __launch_bounds__(256) void k_gather(const int* __restrict__ adj, const int* __restrict__ off,
                                                const uint2* __restrict__ pswg, const float* __restrict__ inv4,
                                                const float* __restrict__ pself4, const unsigned* __restrict__ h32,
                                                const float* __restrict__ bias, float* __restrict__ out, int n) {
  int gid = blockIdx.x * 256 + threadIdx.x;
  int node = gid >> 6, lane = gid & 63;
  if (node >= n) return;
  int head = lane >> 4;
  bool hodd = (head & 1), hhi = (head & 2);
  int o = off[node], oe = off[node + 1];
  float inv = inv4[node * 4 + head];
  float ps = pself4[node * 4 + head];
  unsigned su = h32[((unsigned)node << 6) + lane];
  float acc0 = ps * blo(su), acc1 = ps * bhi(su);
  int j = o;
  for (; j + 8 <= oe; j += 8) {
    int sv[8];
    uint2 wv2[8];
    unsigned hu[8];
#pragma unroll
    for (int k = 0; k < 8; ++k) { sv[k] = adj[j + k]; wv2[k] = pswg[j + k]; }
#pragma unroll
    for (int k = 0; k < 8; ++k) hu[k] = h32[((unsigned)sv[k] << 6) + lane];
#pragma unroll
    for (int k = 0; k < 8; ++k) {
      unsigned v = hhi ? wv2[k].y : wv2[k].x;
      float p = hodd ? bhi(v) : blo(v);
      acc0 += p * blo(hu[k]);
      acc1 += p * bhi(hu[k]);
    }
  }
  for (; j + 2 <= oe; j += 2) {
    int sA = adj[j], sB = adj[j + 1];
    uint2 wA = pswg[j], wB = pswg[j + 1];
    unsigned uA = h32[((unsigned)sA << 6) + lane];
    unsigned uB = h32[((unsigned)sB << 6) + lane];
    unsigned vA = hhi ? wA.y : wA.x, vB = hhi ? wB.y : wB.x;
    float pA = hodd ? bhi(vA) : blo(vA);
    float pB = hodd ? bhi(vB) : blo(vB);
    acc0 += pA * blo(uA) + pB * blo(uB);
    acc1 += pA * bhi(uA) + pB * bhi(uB);
  }
  if (j < oe) {
    int s = adj[j];
    uint2 w = pswg[j];
    unsigned u = h32[((unsigned)s << 6) + lane];
    unsigned v = hhi ? w.y : w.x;
    float p = hodd ? bhi(v) : blo(v);
    acc0 += p * blo(u);
    acc1 += p * bhi(u);
  }
  float2 bb = ((const float2*)bias)[lane];
  ((float2*)(out + (size_t)node * 128))[lane] = make_float2(acc0 * inv + bb.x, acc1 * inv + bb.y);
}

extern "C" void kernel_launch(void* const* d_in, const int* in_sizes, int n_in,
                              void* d_out, int out_size, void* d_ws, size_t ws_size,
                              hipStream_t stream) {
  const float* x     = (const float*)d_in[0];
  const int*   ei    = (const int*)d_in[1];
  const float* W     = (const float*)d_in[2];
  const float* a_src = (const float*)d_in[3];
  const float* a_dst = (const float*)d_in[4];
  const float* bias  = (const float*)d_in[5];
  float* out = (float*)d_out;

  int n = in_sizes[0] / 128;   // IN = 128
  int e = in_sizes[1] / 2;
  int NB = (n + BKT - 1) / BKT;   // dst buckets of 64 nodes
  int m = NB * NBLK;
  int gridA = (m + 255) / 256;
  int CE = (e + NBLK - 1) / NBLK;

  char* ws = (char*)d_ws;
  size_t ofs = 0;
  auto alloc = [&](size_t bytes) { void* p = ws + ofs; ofs = (ofs + bytes + 15) & ~(size_t)15; return p; };
  __bf16* h      = (__bf16*)alloc((size_t)n * 128 * sizeof(__bf16));    // 25.6 MB
  unsigned* h32  = (unsigned*)h;
  float* asrc    = (float*)alloc((size_t)n * 4 * sizeof(float));
  float* adst    = (float*)alloc((size_t)n * 4 * sizeof(float));
  float* inv4    = (float*)alloc((size_t)n * 4 * sizeof(float));
  float* pself4  = (float*)alloc((size_t)n * 4 * sizeof(float));
  int* off       = (int*)alloc((size_t)(n + 1) * sizeof(int));
  int* cnt2      = (int*)alloc((size_t)m * sizeof(int));                // 3.2 MB
  int* bsums     = (int*)alloc((size_t)gridA * sizeof(int));
  int* boffbg    = (int*)alloc((size_t)(NB + 1) * sizeof(int));
  unsigned* ebuf = (unsigned*)alloc((size_t)e * sizeof(unsigned));      // 6.4 MB
  int* adj       = (int*)alloc((size_t)e * sizeof(int));                // 6.4 MB
  uint2* pswg    = (uint2*)alloc((size_t)e * sizeof(uint2));            // 12.8 MB
  __bf16* Wt     = (__bf16*)alloc((size_t)128 * 128 * sizeof(__bf16));  // 32 KB

  hipLaunchKernelGGL(k_wprep, dim3(64), dim3(256), 0, stream, W, Wt);
  hipLaunchKernelGGL(k_gemm, dim3((n + 63) / 64), dim3(256), 0, stream,
                     x, Wt, a_src, a_dst, h, asrc, adst, n);
  hipLaunchKernelGGL(k_hist, dim3(NBLK), dim3(256), 0, stream, ei, cnt2, e, NB, CE);
  hipLaunchKernelGGL(k_scanA, dim3(gridA), dim3(256), 0, stream, cnt2, bsums, m);
  hipLaunchKernelGGL(k_scanB, dim3(1), dim3(256), 0, stream, bsums, gridA);
  hipLaunchKernelGGL(k_scanC, dim3(gridA), dim3(256), 0, stream, cnt2, bsums, boffbg, off, m, NB, n, e);
  hipLaunchKernelGGL(k_fill2, dim3(NBLK), dim3(256), 0, stream, ei, cnt2, ebuf, e, NB, CE);
  hipLaunchKernelGGL(k_csr2, dim3(NB), dim3(256), 0, stream, ebuf, boffbg, asrc, adst,
                     off, adj, pswg, inv4, pself4, n);
  hipLaunchKernelGGL(k_gather, dim3((n * 64 + 255) / 256), dim3(256), 0, stream,
                     adj, off, pswg, inv4, pself4, h32, bias, out, n);
}

// Round 12
// 179.908 us; speedup vs baseline: 1.1710x; 1.1710x over previous
//
#include <hip/hip_runtime.h>
#include <stdint.h>

// GAT layer: N nodes, E edges, IN=128 -> H*C=128, H=4 heads, C=32.
// Pipeline (atomic-free partition, slim sort, exp-in-gather):
//   k_wprep : Wt[n][k] = bf16(W[k][n])
//   k_gemm  : h(bf16) = bf16(x) @ Wt via mfma_f32_16x16x32_bf16 (Wt in swizzled LDS)
//             + fused alpha (asrc/adst via 16-lane shfl reduce of acc regs)
//             + LDS repack -> wide coalesced h stores (64 B/lane)
//   k_hist  : per-(bucket,block) edge histogram via LDS (bucket = dst>>6, 64 nodes)
//   k_scanA/B : hierarchical exclusive scan of cnt2 (block sums in bsums);
//             the +bsums correction is folded in at READ time by fill2/sort
//   k_fill2 : deterministic scatter into ebuf, LDS cursors only (no global atomics)
//   k_sort  : per-bucket counting sort ebuf -> node-sorted adj + off (no weights)
//   k_gather: wave-per-node gather-accumulate; p = exp(lrelu(asrc[s]+adh)) computed
//             inline (asrc L2-resident), online denominator (softmax without
//             max-shift: logits bounded, shift-invariant), 8-deep unrolled
//             independent h-row gathers, single coalesced out write.

#define NBLK 512    // partition blocks
#define BKT 64      // dst nodes per bucket

typedef __bf16 bf16x8 __attribute__((ext_vector_type(8)));
typedef float f32x4 __attribute__((ext_vector_type(4)));

__device__ __forceinline__ float lrelu(float x) { return x >= 0.f ? x : 0.2f * x; }
__device__ __forceinline__ float blo(unsigned u) { return __uint_as_float(u << 16); }
__device__ __forceinline__ float bhi(unsigned u) { return __uint_as_float(u & 0xffff0000u); }

__global__ __launch_bounds__(256) void k_wprep(const float* __restrict__ W, __bf16* __restrict__ Wt) {
  int idx = blockIdx.x * 256 + threadIdx.x;   // grid = 64 blocks covers 128*128
  int nn = idx & 127, k = idx >> 7;
  Wt[nn * 128 + k] = (__bf16)W[k * 128 + nn];
}

__global__ __launch_bounds__(256) void k_gemm(const float* __restrict__ x, const __bf16* __restrict__ Wt,
                                              const float* __restrict__ a_src, const float* __restrict__ a_dst,
                                              __bf16* __restrict__ h, float* __restrict__ asrc,
                                              float* __restrict__ adst, int n) {
  __shared__ __align__(16) char Wl[32768];          // Wt[n][k] bf16, XOR-swizzled
  __shared__ __align__(16) __bf16 hbuf[4][16 * 128]; // per-wave bf16 output tile
  int t = threadIdx.x;
  {
    const float4* s4 = (const float4*)Wt;
    for (int i = t; i < 2048; i += 256) {
      int f = i << 4;
      int nr = f >> 8, c = f & 255;
      *(float4*)(Wl + ((nr << 8) | (c ^ ((nr & 7) << 4)))) = s4[i];
    }
  }
  __syncthreads();
  int wv = t >> 6, lane = t & 63;
  int arow = lane & 15, ag = lane >> 4, c15 = lane & 15;
  float as_t[8], ad_t[8];
#pragma unroll
  for (int tile = 0; tile < 8; ++tile) {
    as_t[tile] = a_src[tile * 16 + c15];
    ad_t[tile] = a_dst[tile * 16 + c15];
  }
  int strip = blockIdx.x * 64 + wv * 16;
  int row = strip + arow;
  float4 fa[8];
  if (row < n) {
    const float4* xr = (const float4*)(x + (size_t)row * 128);
#pragma unroll
    for (int q = 0; q < 4; ++q) {
      fa[2 * q]     = xr[q * 8 + ag * 2];
      fa[2 * q + 1] = xr[q * 8 + ag * 2 + 1];
    }
  } else {
#pragma unroll
    for (int q = 0; q < 8; ++q) fa[q] = make_float4(0.f, 0.f, 0.f, 0.f);
  }
  bf16x8 af[4];
#pragma unroll
  for (int q = 0; q < 4; ++q) {
    af[q][0] = (__bf16)fa[2 * q].x;     af[q][1] = (__bf16)fa[2 * q].y;
    af[q][2] = (__bf16)fa[2 * q].z;     af[q][3] = (__bf16)fa[2 * q].w;
    af[q][4] = (__bf16)fa[2 * q + 1].x; af[q][5] = (__bf16)fa[2 * q + 1].y;
    af[q][6] = (__bf16)fa[2 * q + 1].z; af[q][7] = (__bf16)fa[2 * q + 1].w;
  }
  f32x4 acc[8];
#pragma unroll
  for (int tile = 0; tile < 8; ++tile) acc[tile] = (f32x4){0.f, 0.f, 0.f, 0.f};
#pragma unroll
  for (int q = 0; q < 4; ++q) {
    int gb = (q * 64) + (ag << 4);
#pragma unroll
    for (int tile = 0; tile < 8; ++tile) {
      int nn = tile * 16 + c15;
      bf16x8 bf = *(const bf16x8*)(Wl + ((nn << 8) | (gb ^ ((nn & 7) << 4))));
      acc[tile] = __builtin_amdgcn_mfma_f32_16x16x32_bf16(af[q], bf, acc[tile], 0, 0, 0);
    }
  }
  // fused alpha: per (head, r) reduce acc over the 16 c15 lanes
#pragma unroll
  for (int hh = 0; hh < 4; ++hh) {
#pragma unroll
    for (int r = 0; r < 4; ++r) {
      float vps = acc[2 * hh][r] * as_t[2 * hh] + acc[2 * hh + 1][r] * as_t[2 * hh + 1];
      float vpd = acc[2 * hh][r] * ad_t[2 * hh] + acc[2 * hh + 1][r] * ad_t[2 * hh + 1];
#pragma unroll
      for (int m = 1; m < 16; m <<= 1) {
        vps += __shfl_xor(vps, m, 64);
        vpd += __shfl_xor(vpd, m, 64);
      }
      if (c15 == 0) {
        int ro = strip + ag * 4 + r;
        if (ro < n) { asrc[ro * 4 + hh] = vps; adst[ro * 4 + hh] = vpd; }
      }
    }
  }
  // repack acc -> bf16 LDS tile, then wide coalesced store (64 B per lane)
#pragma unroll
  for (int tile = 0; tile < 8; ++tile) {
#pragma unroll
    for (int r = 0; r < 4; ++r)
      hbuf[wv][(ag * 4 + r) * 128 + tile * 16 + c15] = (__bf16)acc[tile][r];
  }
  int rr = lane >> 2, qq = lane & 3;   // lane covers 64 B (32 bf16) of row rr
  int ro = strip + rr;
  if (ro < n) {
    const float4* src = (const float4*)&hbuf[wv][rr * 128 + qq * 32];
    float4* dst = (float4*)(h + (size_t)ro * 128 + qq * 32);
    dst[0] = src[0];
    dst[1] = src[1];
    dst[2] = src[2];
    dst[3] = src[3];
  }
}

// --- atomic-free bucketed edge partition: bucket = dst >> 6 (64 nodes) ---

__global__ __launch_bounds__(256) void k_hist(const int* __restrict__ ei, int* __restrict__ cnt2,
                                              int e, int NB, int CE) {
  __shared__ int hist[2048];
  int t = threadIdx.x, blk = blockIdx.x;
  for (int j = t; j < NB; j += 256) hist[j] = 0;
  __syncthreads();
  int i0 = blk * CE, i1 = min(e, i0 + CE);
  for (int i = i0 + t; i < i1; i += 256) atomicAdd(&hist[ei[e + i] >> 6], 1);
  __syncthreads();
  for (int j = t; j < NB; j += 256) cnt2[j * NBLK + blk] = hist[j];
}

__global__ __launch_bounds__(256) void k_scanA(int* __restrict__ cnt2, int* __restrict__ bsums, int m) {
  __shared__ int wsum[4];
  int t = threadIdx.x, i = blockIdx.x * 256 + t;
  int wv = t >> 6, lane = t & 63;
  int v = (i < m) ? cnt2[i] : 0;
  int sc = v;
#pragma unroll
  for (int ofs = 1; ofs < 64; ofs <<= 1) {
    int u = __shfl_up(sc, ofs, 64);
    if (lane >= ofs) sc += u;
  }
  if (lane == 63) wsum[wv] = sc;
  __syncthreads();
  int base = 0;
  for (int w = 0; w < wv; ++w) base += wsum[w];
  if (i < m) cnt2[i] = base + sc - v;
  if (t == 255) bsums[blockIdx.x] = base + sc;
}

__global__ __launch_bounds__(256) void k_scanB(int* __restrict__ bsums, int nbs) {
  __shared__ int wsum[4];
  int t = threadIdx.x, wv = t >> 6, lane = t & 63;
  int carry = 0;
  for (int c = 0; c < nbs; c += 256) {
    int i = c + t;
    int v = (i < nbs) ? bsums[i] : 0;
    int sc = v;
#pragma unroll
    for (int ofs = 1; ofs < 64; ofs <<= 1) {
      int u = __shfl_up(sc, ofs, 64);
      if (lane >= ofs) sc += u;
    }
    if (lane == 63) wsum[wv] = sc;
    __syncthreads();
    int base = carry;
    for (int w = 0; w < wv; ++w) base += wsum[w];
    if (i < nbs) bsums[i] = base + sc - v;
    carry += wsum[0] + wsum[1] + wsum[2] + wsum[3];
    __syncthreads();
  }
}

// ebuf scatter; global base = cnt2 (block-exclusive) + bsums (folded here)
__global__ __launch_bounds__(256) void k_fill2(const int* __restrict__ ei, const int* __restrict__ cnt2,
                                               const int* __restrict__ bsums,
                                               unsigned* __restrict__ ebuf, int e, int NB, int CE) {
  __shared__ int cur[2048];
  int t = threadIdx.x, blk = blockIdx.x;
  for (int j = t; j < NB; j += 256) {
    int idx = j * NBLK + blk;
    cur[j] = cnt2[idx] + bsums[idx >> 8];
  }
  __syncthreads();
  int i0 = blk * CE, i1 = min(e, i0 + CE);
  for (int i = i0 + t; i < i1; i += 256) {
    int s = ei[i], d = ei[e + i];
    int pos = atomicAdd(&cur[d >> 6], 1);    // LDS atomic only
    ebuf[pos] = ((unsigned)(d & 63) << 26) | (unsigned)s;
  }
}

// per-bucket counting sort -> node-sorted adj + off (no weights)
__global__ __launch_bounds__(256) void k_sort(const unsigned* __restrict__ ebuf, const int* __restrict__ cnt2,
                                              const int* __restrict__ bsums,
                                              int* __restrict__ off, int* __restrict__ adj, int n, int NB, int e) {
  __shared__ int lcnt[BKT], lcur[BKT];
  int b = blockIdx.x, t = threadIdx.x;
  int wv = t >> 6, lane = t & 63;
  int i0 = b * NBLK;
  int s0 = cnt2[i0] + bsums[i0 >> 8];
  int s1 = e;
  if (b + 1 < NB) { int i1 = (b + 1) * NBLK; s1 = cnt2[i1] + bsums[i1 >> 8]; }
  int cnt = s1 - s0;
  int d0 = b * BKT;
  if (t < BKT) lcnt[t] = 0;
  __syncthreads();
  for (int j = t; j < cnt; j += 256) atomicAdd(&lcnt[ebuf[s0 + j] >> 26], 1);
  __syncthreads();
  if (wv == 0) {                       // 64-lane scan of bucket-local counts
    int v = lcnt[lane];
    int sc = v;
#pragma unroll
    for (int o = 1; o < 64; o <<= 1) {
      int u = __shfl_up(sc, o, 64);
      if (lane >= o) sc += u;
    }
    lcur[lane] = sc - v;
    if (d0 + lane < n) off[d0 + lane] = s0 + sc - v;
  }
  if (b == 0 && t == 0) off[n] = e;
  __syncthreads();
  for (int j = t; j < cnt; j += 256) {
    unsigned u = ebuf[s0 + j];
    int pos = atomicAdd(&lcur[u >> 26], 1);
    adj[s0 + pos] = (int)(u & 0x03FFFFFFu);
  }
}

// wave-per-node gather-accumulate; p computed inline from L2-resident asrc
__global__ __launch_bounds__(256) void k_gather(const int* __restrict__ adj, const int* __restrict__ off,
                                                const float* __restrict__ asrc, const float* __restrict__ adst,
                                                const unsigned* __restrict__ h32,
                                                const float* __restrict__ bias, float* __restrict__ out, int n) {
  int gid = blockIdx.x * 256 + threadIdx.x;
  int node = gid >> 6, lane = gid & 63;
  if (node >= n) return;
  int head = lane >> 4;
  int o = off[node], oe = off[node + 1];
  float adh = adst[node * 4 + head];
  float ps = __expf(lrelu(asrc[node * 4 + head] + adh));   // self loop
  unsigned su = h32[((unsigned)node << 6) + lane];
  float acc0 = ps * blo(su), acc1 = ps * bhi(su), dtot = ps;
  int j = o;
  for (; j + 8 <= oe; j += 8) {
    int sv[8];
    unsigned hu[8];
    float av[8];
#pragma unroll
    for (int k = 0; k < 8; ++k) sv[k] = adj[j + k];
#pragma unroll
    for (int k = 0; k < 8; ++k) {
      hu[k] = h32[((unsigned)sv[k] << 6) + lane];
      av[k] = asrc[sv[k] * 4 + head];
    }
#pragma unroll
    for (int k = 0; k < 8; ++k) {
      float p = __expf(lrelu(av[k] + adh));
      dtot += p;
      acc0 += p * blo(hu[k]);
      acc1 += p * bhi(hu[k]);
    }
  }
  for (; j + 2 <= oe; j += 2) {
    int sA = adj[j], sB = adj[j + 1];
    unsigned uA = h32[((unsigned)sA << 6) + lane];
    unsigned uB = h32[((unsigned)sB << 6) + lane];
    float pA = __expf(lrelu(asrc[sA * 4 + head] + adh));
    float pB = __expf(lrelu(asrc[sB * 4 + head] + adh));
    dtot += pA + pB;
    acc0 += pA * blo(uA) + pB * blo(uB);
    acc1 += pA * bhi(uA) + pB * bhi(uB);
  }
  if (j < oe) {
    int s = adj[j];
    unsigned u = h32[((unsigned)s << 6) + lane];
    float p = __expf(lrelu(asrc[s * 4 + head] + adh));
    dtot += p;
    acc0 += p * blo(u);
    acc1 += p * bhi(u);
  }
  float inv = 1.f / dtot;
  float2 bb = ((const float2*)bias)[lane];
  ((float2*)(out + (size_t)node * 128))[lane] = make_float2(acc0 * inv + bb.x, acc1 * inv + bb.y);
}

extern "C" void kernel_launch(void* const* d_in, const int* in_sizes, int n_in,
                              void* d_out, int out_size, void* d_ws, size_t ws_size,
                              hipStream_t stream) {
  const float* x     = (const float*)d_in[0];
  const int*   ei    = (const int*)d_in[1];
  const float* W     = (const float*)d_in[2];
  const float* a_src = (const float*)d_in[3];
  const float* a_dst = (const float*)d_in[4];
  const float* bias  = (const float*)d_in[5];
  float* out = (float*)d_out;

  int n = in_sizes[0] / 128;   // IN = 128
  int e = in_sizes[1] / 2;
  int NB = (n + BKT - 1) / BKT;   // dst buckets of 64 nodes
  int m = NB * NBLK;
  int gridA = (m + 255) / 256;
  int CE = (e + NBLK - 1) / NBLK;

  char* ws = (char*)d_ws;
  size_t ofs = 0;
  auto alloc = [&](size_t bytes) { void* p = ws + ofs; ofs = (ofs + bytes + 15) & ~(size_t)15; return p; };
  __bf16* h      = (__bf16*)alloc((size_t)n * 128 * sizeof(__bf16));    // 25.6 MB
  unsigned* h32  = (unsigned*)h;
  float* asrc    = (float*)alloc((size_t)n * 4 * sizeof(float));
  float* adst    = (float*)alloc((size_t)n * 4 * sizeof(float));
  int* off       = (int*)alloc((size_t)(n + 1) * sizeof(int));
  int* cnt2      = (int*)alloc((size_t)m * sizeof(int));                // 3.2 MB
  int* bsums     = (int*)alloc((size_t)gridA * sizeof(int));
  unsigned* ebuf = (unsigned*)alloc((size_t)e * sizeof(unsigned));      // 6.4 MB
  int* adj       = (int*)alloc((size_t)e * sizeof(int));                // 6.4 MB
  __bf16* Wt     = (__bf16*)alloc((size_t)128 * 128 * sizeof(__bf16));  // 32 KB

  hipLaunchKernelGGL(k_wprep, dim3(64), dim3(256), 0, stream, W, Wt);
  hipLaunchKernelGGL(k_gemm, dim3((n + 63) / 64), dim3(256), 0, stream,
                     x, Wt, a_src, a_dst, h, asrc, adst, n);
  hipLaunchKernelGGL(k_hist, dim3(NBLK), dim3(256), 0, stream, ei, cnt2, e, NB, CE);
  hipLaunchKernelGGL(k_scanA, dim3(gridA), dim3(256), 0, stream, cnt2, bsums, m);
  hipLaunchKernelGGL(k_scanB, dim3(1), dim3(256), 0, stream, bsums, gridA);
  hipLaunchKernelGGL(k_fill2, dim3(NBLK), dim3(256), 0, stream, ei, cnt2, bsums, ebuf, e, NB, CE);
  hipLaunchKernelGGL(k_sort, dim3(NB), dim3(256), 0, stream, ebuf, cnt2, bsums, off, adj, n, NB, e);
  hipLaunchKernelGGL(k_gather, dim3((n * 64 + 255) / 256), dim3(256), 0, stream,
                     adj, off, asrc, adst, h32, bias, out, n);
}